// Round 5
// baseline (639.277 us; speedup 1.0000x reference)
//
#include <hip/hip_runtime.h>
#include <hip/hip_bf16.h>

// DKVMN: B=128 S=1024 IN=256 M=64 D=128 OUT=128.
// w_t = softmax(x @ (Wr K^T) + br K^T) precomputed (Mv-independent); scan is an
// elementwise affine recurrence; y = sigmoid(r@Wp+bp) deferred to post-GEMM.
// R10: k2 rewritten as LDS-staged scan. R4 counters showed k2 at 248us with
//      VALUBusy 59% / VGPR 44: compiler sank the reg ping-pong loads (no bank
//      regs allocated) -> ~900cy HBM stall per 8-step batch, plus 6 unpack
//      instr/step. Now: 16-step tiles staged to LDS double-buffer via
//      global_load_lds (zero VGPR, un-sinkable), one barrier/tile; w stored
//      fp32 by k1 (kills 4 unp/step); per-step = ds_read_b32 + ds_read_b128 +
//      2 unp + 12 fma + 4 shfl + 4 add. k1/k3 unchanged from R9.

#define B_   128
#define S_   1024
#define IN_  256
#define M_   64
#define D_   128
#define OUT_ 128
#define NROWS_ (B_ * S_)   // 131072 rows

typedef __hip_bfloat16 bf16;
typedef unsigned int uint32;
typedef __attribute__((ext_vector_type(8))) short s16x8;
typedef __attribute__((ext_vector_type(4))) float f32x4;

__device__ __forceinline__ float tof(bf16 v) { return __bfloat162float(v); }
__device__ __forceinline__ bf16  tob(float v) { return __float2bfloat16(v); }
__device__ __forceinline__ float ldf(const float* p, long i) { return p[i]; }
__device__ __forceinline__ float ldf(const bf16* p, long i)  { return tof(p[i]); }
__device__ __forceinline__ void  stf(float* p, long i, float v) { p[i] = v; }
__device__ __forceinline__ void  stf(bf16* p, long i, float v)  { p[i] = tob(v); }
__device__ __forceinline__ void  unp(uint32 u, float& lo, float& hi) {
  lo = __uint_as_float(u << 16);
  hi = __uint_as_float(u & 0xFFFF0000u);
}
__device__ __forceinline__ uint32 pk(float lo, float hi) {
  union { bf16 h; unsigned short u; } a, b;
  a.h = tob(lo); b.h = tob(hi);
  return (uint32)a.u | ((uint32)b.u << 16);
}
// split two fp32 into packed bf16 hi-words + packed bf16 residual-words
__device__ __forceinline__ void split2(float f0, float f1, uint32& h, uint32& l) {
  union { bf16 b; unsigned short u; } a0, a1;
  a0.b = tob(f0); a1.b = tob(f1);
  h = (uint32)a0.u | ((uint32)a1.u << 16);
  const float r0 = f0 - tof(a0.b);
  const float r1 = f1 - tof(a1.b);
  l = pk(r0, r1);
}
// async global -> LDS, 16B per lane (dest = lds base + lane*16)
__device__ __forceinline__ void gl16(const void* g, void* s) {
  __builtin_amdgcn_global_load_lds(
      (const __attribute__((address_space(1))) void*)g,
      (__attribute__((address_space(3))) void*)s, 16, 0, 0);
}

// ---------------- probe: decide fp32 (flag=1) vs bf16 (flag=0) inputs ----------------
__global__ __launch_bounds__(256) void k_probe(const uint32* __restrict__ xw,
                                               int* __restrict__ flag) {
  __shared__ int s[256];
  const int tid = threadIdx.x;
  int sc = 0;
#pragma unroll
  for (int k = 0; k < 8; ++k) {
    const uint32 u = xw[tid * 8 + k];
    const float v = __uint_as_float(u << 16);  // low 16 bits as bf16
    if (!(fabsf(v) < 4.0f)) sc++;              // catches big values AND NaN/Inf
  }
  s[tid] = sc;
  __syncthreads();
  for (int o = 128; o > 0; o >>= 1) {
    if (tid < o) s[tid] += s[tid + o];
    __syncthreads();
  }
  if (tid == 0) *flag = (s[0] > 64) ? 1 : 0;
}

// ---------------- K0: fold Wk = Wr @ K^T (256x64), bk = br @ K^T (64) ----------------
template <typename T>
__device__ void k0_body(const T* Wr, const T* br, const T* K,
                        float* Wk, float* bk) {
  const int idx = blockIdx.x * 256 + threadIdx.x;
  if (idx < IN_ * M_) {
    const int i = idx >> 6, m = idx & 63;
    float acc = 0.f;
    for (int d = 0; d < D_; ++d)
      acc = fmaf(ldf(Wr, (long)i * D_ + d), ldf(K, (long)m * D_ + d), acc);
    Wk[idx] = acc;  // idx == i*M_+m
  } else if (idx < IN_ * M_ + M_) {
    const int m = idx - IN_ * M_;
    float acc = 0.f;
    for (int d = 0; d < D_; ++d)
      acc = fmaf(ldf(br, d), ldf(K, (long)m * D_ + d), acc);
    bk[m] = acc;
  }
}

__global__ __launch_bounds__(256) void k0_fold(const void* Wr, const void* br,
                                               const void* K, float* Wk, float* bk,
                                               const int* flag) {
  if (*flag) k0_body<float>((const float*)Wr, (const float*)br, (const float*)K, Wk, bk);
  else       k0_body<bf16>((const bf16*)Wr, (const bf16*)br, (const bf16*)K, Wk, bk);
}

// ---------------- K0b: pack weights in MFMA FRAGMENT-LINEAR order -------------------
// Wcat (N=192,K=256): frag idx = ((ct*8 + kst)*64 + lane)*8 + j, lane=quad*16+l15;
//   element = Wcat[n=ct*16+l15][k=kst*32+quad*8+j], n<128 -> Ww^T, else (WrK^T)^T.
// Wp (N=128,K=128):  frag idx = ((ct*4 + kst)*64 + lane)*8 + j, same mapping.
// 49152 + 16384 = 65536 positions = grid 256x256. flag==1 also writes residuals.
__global__ __launch_bounds__(256) void k0b_pack(const void* Ww, const void* Wp,
                                                const float* Wk, bf16* WTh, bf16* WTl,
                                                bf16* WpTh, bf16* WpTl,
                                                const int* flag) {
  const int f = *flag;
  const int idx = blockIdx.x * 256 + threadIdx.x;
  if (idx < 12 * 8 * 64 * 8) {
    const int j = idx & 7, lane = (idx >> 3) & 63;
    const int kst = (idx >> 9) & 7, ct = idx >> 12;
    const int l15 = lane & 15, quad = lane >> 4;
    const int n = ct * 16 + l15;
    const int k = kst * 32 + quad * 8 + j;
    float v;
    if (f) v = (n < 128) ? ((const float*)Ww)[k * 128 + n] : Wk[k * 64 + (n - 128)];
    else   v = (n < 128) ? tof(((const bf16*)Ww)[k * 128 + n]) : Wk[k * 64 + (n - 128)];
    const bf16 h = tob(v);
    WTh[idx] = h;
    if (f) WTl[idx] = tob(v - tof(h));
  } else {
    const int o = idx - 12 * 8 * 64 * 8;
    const int j = o & 7, lane = (o >> 3) & 63;
    const int kst = (o >> 9) & 3, ct = o >> 11;
    const int l15 = lane & 15, quad = lane >> 4;
    const int n = ct * 16 + l15;
    const int k = kst * 32 + quad * 8 + j;
    float v;
    if (f) v = ((const float*)Wp)[k * 128 + n];
    else   v = tof(((const bf16*)Wp)[k * 128 + n]);
    const bf16 h = tob(v);
    WpTh[o] = h;
    if (f) WpTl[o] = tob(v - tof(h));
  }
}

// ---------------- K1 (MFMA): [RC x 256]@[256x192] + epilogue ------------------------
// Block = 64 rows (4 waves x 16). a-frag: lane holds x[row=l15][k=quad*8+j];
// b-frag loaded fragment-linear (coalesced 1KB per wave instruction).
// F32: x fp32 split into bf16 hi/lo; acc += ah*bh + al*bh + ah*bl (bf16x3).
template <bool F32>
__device__ void k1_body(const void* x, const void* bw, const float* bk,
                        const bf16* __restrict__ WTh, const bf16* __restrict__ WTl,
                        uint32* __restrict__ ea_all, float* __restrict__ w_all,
                        int chunk, int TL, int tshift) {
  const int tid = threadIdx.x;
  const int wave = tid >> 6, lane = tid & 63;
  const int l15 = lane & 15, quad = lane >> 4;
  const int b = blockIdx.x >> tshift;
  const int tb = blockIdx.x & ((1 << tshift) - 1);
  const int t0 = tb * 64 + wave * 16;
  const long lr0 = (long)b * TL + t0;                     // chunk-local row base
  const long ar0 = (long)b * S_ + (long)chunk * TL + t0;  // absolute row base

  // load 8 a-frags (K=256)
  s16x8 afh[8], afl[8];
  if constexpr (F32) {
    const float* xr = (const float*)x + (ar0 + l15) * (long)IN_ + quad * 8;
#pragma unroll
    for (int k = 0; k < 8; ++k) {
      const float4 u0 = *(const float4*)(xr + k * 32);
      const float4 u1 = *(const float4*)(xr + k * 32 + 4);
      union { s16x8 v; uint32 u[4]; } H, L;
      split2(u0.x, u0.y, H.u[0], L.u[0]);
      split2(u0.z, u0.w, H.u[1], L.u[1]);
      split2(u1.x, u1.y, H.u[2], L.u[2]);
      split2(u1.z, u1.w, H.u[3], L.u[3]);
      afh[k] = H.v;
      afl[k] = L.v;
    }
  } else {
    const bf16* xr = (const bf16*)x + (ar0 + l15) * (long)IN_ + quad * 8;
#pragma unroll
    for (int k = 0; k < 8; ++k) afh[k] = *(const s16x8*)(xr + k * 32);
  }

  f32x4 acc[12];
#pragma unroll
  for (int ct = 0; ct < 12; ++ct) acc[ct] = (f32x4){0.f, 0.f, 0.f, 0.f};

  // fragment-linear B: base + (ct*8+k)*512 + lane*8
  const bf16* fbh = WTh + lane * 8;
  const bf16* fbl = WTl + lane * 8;
#pragma unroll
  for (int ct = 0; ct < 12; ++ct) {
#pragma unroll
    for (int k = 0; k < 8; ++k) {
      const s16x8 bh = *(const s16x8*)(fbh + (ct * 8 + k) * 512);
      acc[ct] = __builtin_amdgcn_mfma_f32_16x16x32_bf16(afh[k], bh, acc[ct], 0, 0, 0);
      if constexpr (F32) {
        const s16x8 bl = *(const s16x8*)(fbl + (ct * 8 + k) * 512);
        acc[ct] = __builtin_amdgcn_mfma_f32_16x16x32_bf16(afl[k], bh, acc[ct], 0, 0, 0);
        acc[ct] = __builtin_amdgcn_mfma_f32_16x16x32_bf16(afh[k], bl, acc[ct], 0, 0, 0);
      }
    }
  }

  // epilogue: v tiles 0..7 -> e,a packed; score tiles 8..11 -> softmax (w fp32)
#pragma unroll
  for (int ct = 0; ct < 8; ++ct) {
    const int col = ct * 16 + l15;
    float bb;
    if constexpr (F32) bb = ((const float*)bw)[col];
    else               bb = tof(((const bf16*)bw)[col]);
#pragma unroll
    for (int r = 0; r < 4; ++r) {
      const float v = acc[ct][r] + bb;
      const float sg = 1.0f / (1.0f + exp2f(-1.44269504f * v));
      const float th = 1.0f - 2.0f / (exp2f(2.88539008f * v) + 1.0f);
      ea_all[(lr0 + quad * 4 + r) * D_ + col] = pk(sg, th);
    }
  }
  float bks[4];
#pragma unroll
  for (int g = 0; g < 4; ++g) bks[g] = bk[g * 16 + l15];
#pragma unroll
  for (int r = 0; r < 4; ++r) {
    float s[4];
    float mx = -1e30f;
#pragma unroll
    for (int g = 0; g < 4; ++g) {
      s[g] = acc[8 + g][r] + bks[g];
      mx = fmaxf(mx, s[g]);
    }
#pragma unroll
    for (int off = 1; off < 16; off <<= 1) mx = fmaxf(mx, __shfl_xor(mx, off, 64));
    float ex[4], sum = 0.f;
#pragma unroll
    for (int g = 0; g < 4; ++g) {
      ex[g] = exp2f(1.44269504f * (s[g] - mx));
      sum += ex[g];
    }
#pragma unroll
    for (int off = 1; off < 16; off <<= 1) sum += __shfl_xor(sum, off, 64);
    const float inv = 1.0f / sum;
    const long lr = lr0 + quad * 4 + r;
#pragma unroll
    for (int g = 0; g < 4; ++g)
      w_all[lr * M_ + g * 16 + l15] = ex[g] * inv;
  }
}

__global__ __launch_bounds__(256, 2) void k1_mfma(const void* x, const void* bw,
                                                  const float* bk, const bf16* WTh,
                                                  const bf16* WTl, uint32* ea_all,
                                                  float* w_all, int chunk, int TL,
                                                  int tshift,
                                                  const int* __restrict__ flag) {
  if (*flag) k1_body<true>(x, bw, bk, WTh, WTl, ea_all, w_all, chunk, TL, tshift);
  else       k1_body<false>(x, bw, bk, WTh, WTl, ea_all, w_all, chunk, TL, tshift);
}

// ---------------- K2: LDS-staged scan. grid = B*8 x 256 threads ---------------------
// Block owns (b = blk&127, d-range = (blk>>7)*16 .. +16). Wave w covers
// d = dgHi*16 + w*4 + dl; lane = mg*4+dl, mg owns m = mg*4..+4.
// 16-step tiles double-buffered in LDS: ea 1KB (1 gl16) + w fp32 4KB (4 gl16),
// staged by wave 0 one tile ahead; one __syncthreads per tile.
// Per step: ds_read_b32 (broadcast) + ds_read_b128 + 2 unp + 12 fma + 4 shfl.
template <typename T>
__device__ void k2_body(const T* Mv0, const uint32* ea_all, const float* w_all,
                        float* MvS, T* r_out, int chunk, int TL, int TC) {
  const int tid = threadIdx.x;
  const int wave = tid >> 6, lane = tid & 63;
  const int mg = lane >> 2, dl = lane & 3;
  const int b = blockIdx.x & 127;
  const int dgHi = blockIdx.x >> 7;        // 0..7
  const int q = wave * 4 + dl;             // 0..15 within block d-range
  const int d = dgHi * 16 + q;
  const int m0 = mg * 4;

  __shared__ uint32 sEA[2][16][16];  // [buf][t][q]      2 KB
  __shared__ float  sW[2][16][64];   // [buf][t][m]      8 KB

  float Mv[4];
  if (chunk == 0) {
#pragma unroll
    for (int j = 0; j < 4; ++j)
      Mv[j] = ldf(Mv0, (long)(m0 + j) * D_ + d);
  } else {
#pragma unroll
    for (int j = 0; j < 4; ++j)
      Mv[j] = MvS[((long)b * M_ + m0 + j) * D_ + d];
  }

  const long lrbase = (long)b * TL;                     // chunk-local
  const long arbase = (long)b * S_ + (long)chunk * TL;  // absolute

  // staging lambdas (wave 0 only). dest = lds base + lane*16.
  const int sl2 = lane >> 2, sl4 = lane >> 4;
  const int eac = (lane & 3) * 4;    // ea col group
  const int wmc = (lane & 15) * 4;   // w col group
  auto stage = [&](int buf, int t0) {
    gl16(&ea_all[(lrbase + t0 + sl2) * D_ + dgHi * 16 + eac], &sEA[buf][0][0]);
#pragma unroll
    for (int i = 0; i < 4; ++i)
      gl16(&w_all[(lrbase + t0 + i * 4 + sl4) * M_ + wmc], &sW[buf][i * 4][0]);
  };

  if (wave == 0) stage(0, 0);
  __syncthreads();

  const int NT = TL / 16;
  for (int kk = 0; kk < NT; ++kk) {
    const int cur = kk & 1;
    if (wave == 0 && kk + 1 < NT) stage(cur ^ 1, (kk + 1) * 16);
    const long ab = arbase + kk * 16;
#pragma unroll
    for (int t = 0; t < 16; ++t) {
      float e, a;
      unp(sEA[cur][t][q], e, a);
      const float4 wv = *(const float4*)&sW[cur][t][m0];
      float r = 0.f;
#pragma unroll
      for (int j = 0; j < 4; ++j) {
        r = fmaf(wv[j == 0 ? 0 : j == 1 ? 1 : j == 2 ? 2 : 3], Mv[j], r);
        Mv[j] = fmaf((&wv.x)[j], fmaf(-e, Mv[j], a), Mv[j]);
      }
      r += __shfl_xor(r, 4, 64);
      r += __shfl_xor(r, 8, 64);
      r += __shfl_xor(r, 16, 64);
      r += __shfl_xor(r, 32, 64);
      if (mg == 0) stf(r_out, (ab + t) * D_ + d, r);
    }
    __syncthreads();
  }

  if (chunk < TC - 1) {
#pragma unroll
    for (int j = 0; j < 4; ++j)
      MvS[((long)b * M_ + m0 + j) * D_ + d] = Mv[j];
  }
}

__global__ __launch_bounds__(256) void k2_scan(const void* Mv0, const uint32* ea_all,
                                               const float* w_all, float* MvS,
                                               void* r_out, int chunk, int TL,
                                               int TC, const int* flag) {
  if (*flag) k2_body<float>((const float*)Mv0, ea_all, w_all, MvS,
                            (float*)r_out, chunk, TL, TC);
  else       k2_body<bf16>((const bf16*)Mv0, ea_all, w_all, MvS,
                           (bf16*)r_out, chunk, TL, TC);
}

// ---------------- K3 (MFMA): y = sigmoid(r @ Wp + bp), in place ----------------------
// F32: r fp32 in d_out, split to bf16 hi/lo in-register, bf16x3 MFMA, write fp32 y
// in place. Each wave owns a disjoint 16-row tile: all reads land in registers
// before any store, so in-place is race-free. B-frags fragment-linear.
template <bool F32>
__device__ void k3_body(const bf16* __restrict__ WpTh, const bf16* __restrict__ WpTl,
                        const void* bpv, void* iov) {
  const int tid = threadIdx.x;
  const int wave = tid >> 6, lane = tid & 63;
  const int l15 = lane & 15, quad = lane >> 4;
  const long row0 = (long)blockIdx.x * 64 + wave * 16;

  s16x8 afh[4], afl[4];
  if constexpr (F32) {
    const float* rr = (const float*)iov + (row0 + l15) * D_ + quad * 8;
#pragma unroll
    for (int k = 0; k < 4; ++k) {
      const float4 u0 = *(const float4*)(rr + k * 32);
      const float4 u1 = *(const float4*)(rr + k * 32 + 4);
      union { s16x8 v; uint32 u[4]; } H, L;
      split2(u0.x, u0.y, H.u[0], L.u[0]);
      split2(u0.z, u0.w, H.u[1], L.u[1]);
      split2(u1.x, u1.y, H.u[2], L.u[2]);
      split2(u1.z, u1.w, H.u[3], L.u[3]);
      afh[k] = H.v;
      afl[k] = L.v;
    }
  } else {
    const bf16* rr = (const bf16*)iov + (row0 + l15) * D_ + quad * 8;
#pragma unroll
    for (int k = 0; k < 4; ++k) afh[k] = *(const s16x8*)(rr + k * 32);
  }

  f32x4 acc[8];
#pragma unroll
  for (int ct = 0; ct < 8; ++ct) acc[ct] = (f32x4){0.f, 0.f, 0.f, 0.f};
  const bf16* fbh = WpTh + lane * 8;
  const bf16* fbl = WpTl + lane * 8;
#pragma unroll
  for (int ct = 0; ct < 8; ++ct) {
#pragma unroll
    for (int k = 0; k < 4; ++k) {
      const s16x8 bh = *(const s16x8*)(fbh + (ct * 4 + k) * 512);
      acc[ct] = __builtin_amdgcn_mfma_f32_16x16x32_bf16(afh[k], bh, acc[ct], 0, 0, 0);
      if constexpr (F32) {
        const s16x8 bl = *(const s16x8*)(fbl + (ct * 4 + k) * 512);
        acc[ct] = __builtin_amdgcn_mfma_f32_16x16x32_bf16(afl[k], bh, acc[ct], 0, 0, 0);
        acc[ct] = __builtin_amdgcn_mfma_f32_16x16x32_bf16(afh[k], bl, acc[ct], 0, 0, 0);
      }
    }
  }
#pragma unroll
  for (int ct = 0; ct < 8; ++ct) {
    const int col = ct * 16 + l15;
    float bb;
    if constexpr (F32) bb = ((const float*)bpv)[col];
    else               bb = tof(((const bf16*)bpv)[col]);
#pragma unroll
    for (int r = 0; r < 4; ++r) {
      const float y = 1.0f / (1.0f + exp2f(-1.44269504f * (acc[ct][r] + bb)));
      if constexpr (F32)
        ((float*)iov)[(row0 + quad * 4 + r) * OUT_ + col] = y;
      else
        ((bf16*)iov)[(row0 + quad * 4 + r) * OUT_ + col] = tob(y);
    }
  }
}

__global__ __launch_bounds__(256, 2) void k3_mfma(const bf16* __restrict__ WpTh,
                                                  const bf16* __restrict__ WpTl,
                                                  const void* bpv, void* iov,
                                                  const int* __restrict__ flag) {
  if (*flag) k3_body<true>(WpTh, WpTl, bpv, iov);
  else       k3_body<false>(WpTh, WpTl, bpv, iov);
}

extern "C" void kernel_launch(void* const* d_in, const int* in_sizes, int n_in,
                              void* d_out, int out_size, void* d_ws, size_t ws_size,
                              hipStream_t stream) {
  const void* x   = d_in[0];
  const void* mk  = d_in[1];
  const void* mv  = d_in[2];
  const void* Wr  = d_in[3];
  const void* br  = d_in[4];
  const void* Ww  = d_in[5];
  const void* bwv = d_in[6];
  const void* Wp  = d_in[7];
  const void* bp  = d_in[8];

  // Fixed-region layout: flag | Wk fp32 | bk fp32 | WTh/WTl | WpTh/WpTl
  char* ws = (char*)d_ws;
  int*    flag = (int*)ws;
  float*  Wk   = (float*)(ws + 16);
  float*  bk   = (float*)(ws + 16 + 65536);
  bf16*   WTh  = (bf16*)(ws + 65808);
  bf16*   WTl  = WTh + 192 * 256;
  bf16*   WpTh = WTl + 192 * 256;
  bf16*   WpTl = WpTh + 128 * 128;
  char*   dyn  = (char*)(WpTl + 128 * 128);  // ws + 327,952
  const size_t fixed = (size_t)(dyn - ws);

  // Pick TC = smallest chunk count whose buffers fit ws_size.
  // Per chunk-row: ea u32 (D*4 B) + w fp32 (M*4 B).
  int TC = 16;
  for (int c = 1; c <= 16; c <<= 1) {
    const size_t rc = (size_t)NROWS_ / c;
    const size_t need = fixed + rc * (D_ * 4 + M_ * 4) +
                        (c > 1 ? (size_t)B_ * M_ * D_ * 4 : 0) + 1024;
    if (need <= ws_size) { TC = c; break; }
  }
  const int TL = S_ / TC;
  const int tshift = __builtin_ctz(TL / 64);
  const size_t RC = (size_t)NROWS_ / TC;

  uint32* ea_all = (uint32*)dyn;
  float*  w_all  = (float*)(ea_all + RC * D_);
  float*  MvS    = (float*)(w_all + RC * M_);

  k_probe<<<1, 256, 0, stream>>>((const uint32*)x, flag);
  k0_fold<<<(IN_ * M_ + M_ + 255) / 256, 256, 0, stream>>>(Wr, br, mk, Wk, bk, flag);
  k0b_pack<<<256, 256, 0, stream>>>(Ww, Wp, Wk, WTh, WTl, WpTh, WpTl, flag);
  for (int c = 0; c < TC; ++c) {
    k1_mfma<<<(int)(RC / 64), 256, 0, stream>>>(x, bwv, bk, WTh, WTl, ea_all, w_all,
                                                c, TL, tshift, flag);
    k2_scan<<<B_ * 8, 256, 0, stream>>>(mv, ea_all, w_all, MvS, d_out, c, TL, TC,
                                        flag);
  }
  k3_mfma<<<NROWS_ / 64, 256, 0, stream>>>(WpTh, WpTl, bp, d_out, flag);
}

// Round 7
// 615.885 us; speedup vs baseline: 1.0380x; 1.0380x over previous
//
#include <hip/hip_runtime.h>
#include <hip/hip_bf16.h>

// DKVMN: B=128 S=1024 IN=256 M=64 D=128 OUT=128.
// w_t = softmax(x @ (Wr K^T) + br K^T) precomputed (Mv-independent); scan is an
// elementwise affine recurrence; y = sigmoid(r@Wp+bp) deferred to post-GEMM.
// R12: resubmit of R11 (round-6 "container failed twice" diagnosed as infra:
//      R2's identical-layout kernel also "failed", yet R3 ran the same 84MB
//      TC=1 layout clean; R11's gl16 lane->LDS mappings audit correct).
//      k2: 8m x 1d per thread (8 Mv regs, 24 FMA/step), lane = mg(8) x
//      dloc(8); w via 2 ds_read_b128 (2-way alias = free), ea via broadcast
//      ds_read_b32; reduce = 3 shfl; grid = B*4 x 256. LDS double-buffer
//      staging via gl16 (waves 0-2), one barrier/tile. k1/k3 = R9/R10 form.

#define B_   128
#define S_   1024
#define IN_  256
#define M_   64
#define D_   128
#define OUT_ 128
#define NROWS_ (B_ * S_)   // 131072 rows

typedef __hip_bfloat16 bf16;
typedef unsigned int uint32;
typedef __attribute__((ext_vector_type(8))) short s16x8;
typedef __attribute__((ext_vector_type(4))) float f32x4;

__device__ __forceinline__ float tof(bf16 v) { return __bfloat162float(v); }
__device__ __forceinline__ bf16  tob(float v) { return __float2bfloat16(v); }
__device__ __forceinline__ float ldf(const float* p, long i) { return p[i]; }
__device__ __forceinline__ float ldf(const bf16* p, long i)  { return tof(p[i]); }
__device__ __forceinline__ void  stf(float* p, long i, float v) { p[i] = v; }
__device__ __forceinline__ void  stf(bf16* p, long i, float v)  { p[i] = tob(v); }
__device__ __forceinline__ void  unp(uint32 u, float& lo, float& hi) {
  lo = __uint_as_float(u << 16);
  hi = __uint_as_float(u & 0xFFFF0000u);
}
__device__ __forceinline__ uint32 pk(float lo, float hi) {
  union { bf16 h; unsigned short u; } a, b;
  a.h = tob(lo); b.h = tob(hi);
  return (uint32)a.u | ((uint32)b.u << 16);
}
// split two fp32 into packed bf16 hi-words + packed bf16 residual-words
__device__ __forceinline__ void split2(float f0, float f1, uint32& h, uint32& l) {
  union { bf16 b; unsigned short u; } a0, a1;
  a0.b = tob(f0); a1.b = tob(f1);
  h = (uint32)a0.u | ((uint32)a1.u << 16);
  const float r0 = f0 - tof(a0.b);
  const float r1 = f1 - tof(a1.b);
  l = pk(r0, r1);
}
// async global -> LDS, 16B per lane (dest = lds base + lane*16)
__device__ __forceinline__ void gl16(const void* g, void* s) {
  __builtin_amdgcn_global_load_lds(
      (const __attribute__((address_space(1))) void*)g,
      (__attribute__((address_space(3))) void*)s, 16, 0, 0);
}

// ---------------- probe: decide fp32 (flag=1) vs bf16 (flag=0) inputs ----------------
__global__ __launch_bounds__(256) void k_probe(const uint32* __restrict__ xw,
                                               int* __restrict__ flag) {
  __shared__ int s[256];
  const int tid = threadIdx.x;
  int sc = 0;
#pragma unroll
  for (int k = 0; k < 8; ++k) {
    const uint32 u = xw[tid * 8 + k];
    const float v = __uint_as_float(u << 16);  // low 16 bits as bf16
    if (!(fabsf(v) < 4.0f)) sc++;              // catches big values AND NaN/Inf
  }
  s[tid] = sc;
  __syncthreads();
  for (int o = 128; o > 0; o >>= 1) {
    if (tid < o) s[tid] += s[tid + o];
    __syncthreads();
  }
  if (tid == 0) *flag = (s[0] > 64) ? 1 : 0;
}

// ---------------- K0: fold Wk = Wr @ K^T (256x64), bk = br @ K^T (64) ----------------
template <typename T>
__device__ void k0_body(const T* Wr, const T* br, const T* K,
                        float* Wk, float* bk) {
  const int idx = blockIdx.x * 256 + threadIdx.x;
  if (idx < IN_ * M_) {
    const int i = idx >> 6, m = idx & 63;
    float acc = 0.f;
    for (int d = 0; d < D_; ++d)
      acc = fmaf(ldf(Wr, (long)i * D_ + d), ldf(K, (long)m * D_ + d), acc);
    Wk[idx] = acc;  // idx == i*M_+m
  } else if (idx < IN_ * M_ + M_) {
    const int m = idx - IN_ * M_;
    float acc = 0.f;
    for (int d = 0; d < D_; ++d)
      acc = fmaf(ldf(br, d), ldf(K, (long)m * D_ + d), acc);
    bk[m] = acc;
  }
}

__global__ __launch_bounds__(256) void k0_fold(const void* Wr, const void* br,
                                               const void* K, float* Wk, float* bk,
                                               const int* flag) {
  if (*flag) k0_body<float>((const float*)Wr, (const float*)br, (const float*)K, Wk, bk);
  else       k0_body<bf16>((const bf16*)Wr, (const bf16*)br, (const bf16*)K, Wk, bk);
}

// ---------------- K0b: pack weights in MFMA FRAGMENT-LINEAR order -------------------
// Wcat (N=192,K=256): frag idx = ((ct*8 + kst)*64 + lane)*8 + j, lane=quad*16+l15;
//   element = Wcat[n=ct*16+l15][k=kst*32+quad*8+j], n<128 -> Ww^T, else (WrK^T)^T.
// Wp (N=128,K=128):  frag idx = ((ct*4 + kst)*64 + lane)*8 + j, same mapping.
// 49152 + 16384 = 65536 positions = grid 256x256. flag==1 also writes residuals.
__global__ __launch_bounds__(256) void k0b_pack(const void* Ww, const void* Wp,
                                                const float* Wk, bf16* WTh, bf16* WTl,
                                                bf16* WpTh, bf16* WpTl,
                                                const int* flag) {
  const int f = *flag;
  const int idx = blockIdx.x * 256 + threadIdx.x;
  if (idx < 12 * 8 * 64 * 8) {
    const int j = idx & 7, lane = (idx >> 3) & 63;
    const int kst = (idx >> 9) & 7, ct = idx >> 12;
    const int l15 = lane & 15, quad = lane >> 4;
    const int n = ct * 16 + l15;
    const int k = kst * 32 + quad * 8 + j;
    float v;
    if (f) v = (n < 128) ? ((const float*)Ww)[k * 128 + n] : Wk[k * 64 + (n - 128)];
    else   v = (n < 128) ? tof(((const bf16*)Ww)[k * 128 + n]) : Wk[k * 64 + (n - 128)];
    const bf16 h = tob(v);
    WTh[idx] = h;
    if (f) WTl[idx] = tob(v - tof(h));
  } else {
    const int o = idx - 12 * 8 * 64 * 8;
    const int j = o & 7, lane = (o >> 3) & 63;
    const int kst = (o >> 9) & 3, ct = o >> 11;
    const int l15 = lane & 15, quad = lane >> 4;
    const int n = ct * 16 + l15;
    const int k = kst * 32 + quad * 8 + j;
    float v;
    if (f) v = ((const float*)Wp)[k * 128 + n];
    else   v = tof(((const bf16*)Wp)[k * 128 + n]);
    const bf16 h = tob(v);
    WpTh[o] = h;
    if (f) WpTl[o] = tob(v - tof(h));
  }
}

// ---------------- K1 (MFMA): [RC x 256]@[256x192] + epilogue ------------------------
// Block = 64 rows (4 waves x 16). a-frag: lane holds x[row=l15][k=quad*8+j];
// b-frag loaded fragment-linear (coalesced 1KB per wave instruction).
// F32: x fp32 split into bf16 hi/lo; acc += ah*bh + al*bh + ah*bl (bf16x3).
template <bool F32>
__device__ void k1_body(const void* x, const void* bw, const float* bk,
                        const bf16* __restrict__ WTh, const bf16* __restrict__ WTl,
                        uint32* __restrict__ ea_all, float* __restrict__ w_all,
                        int chunk, int TL, int tshift) {
  const int tid = threadIdx.x;
  const int wave = tid >> 6, lane = tid & 63;
  const int l15 = lane & 15, quad = lane >> 4;
  const int b = blockIdx.x >> tshift;
  const int tb = blockIdx.x & ((1 << tshift) - 1);
  const int t0 = tb * 64 + wave * 16;
  const long lr0 = (long)b * TL + t0;                     // chunk-local row base
  const long ar0 = (long)b * S_ + (long)chunk * TL + t0;  // absolute row base

  // load 8 a-frags (K=256)
  s16x8 afh[8], afl[8];
  if constexpr (F32) {
    const float* xr = (const float*)x + (ar0 + l15) * (long)IN_ + quad * 8;
#pragma unroll
    for (int k = 0; k < 8; ++k) {
      const float4 u0 = *(const float4*)(xr + k * 32);
      const float4 u1 = *(const float4*)(xr + k * 32 + 4);
      union { s16x8 v; uint32 u[4]; } H, L;
      split2(u0.x, u0.y, H.u[0], L.u[0]);
      split2(u0.z, u0.w, H.u[1], L.u[1]);
      split2(u1.x, u1.y, H.u[2], L.u[2]);
      split2(u1.z, u1.w, H.u[3], L.u[3]);
      afh[k] = H.v;
      afl[k] = L.v;
    }
  } else {
    const bf16* xr = (const bf16*)x + (ar0 + l15) * (long)IN_ + quad * 8;
#pragma unroll
    for (int k = 0; k < 8; ++k) afh[k] = *(const s16x8*)(xr + k * 32);
  }

  f32x4 acc[12];
#pragma unroll
  for (int ct = 0; ct < 12; ++ct) acc[ct] = (f32x4){0.f, 0.f, 0.f, 0.f};

  // fragment-linear B: base + (ct*8+k)*512 + lane*8
  const bf16* fbh = WTh + lane * 8;
  const bf16* fbl = WTl + lane * 8;
#pragma unroll
  for (int ct = 0; ct < 12; ++ct) {
#pragma unroll
    for (int k = 0; k < 8; ++k) {
      const s16x8 bh = *(const s16x8*)(fbh + (ct * 8 + k) * 512);
      acc[ct] = __builtin_amdgcn_mfma_f32_16x16x32_bf16(afh[k], bh, acc[ct], 0, 0, 0);
      if constexpr (F32) {
        const s16x8 bl = *(const s16x8*)(fbl + (ct * 8 + k) * 512);
        acc[ct] = __builtin_amdgcn_mfma_f32_16x16x32_bf16(afl[k], bh, acc[ct], 0, 0, 0);
        acc[ct] = __builtin_amdgcn_mfma_f32_16x16x32_bf16(afh[k], bl, acc[ct], 0, 0, 0);
      }
    }
  }

  // epilogue: v tiles 0..7 -> e,a packed; score tiles 8..11 -> softmax (w fp32)
#pragma unroll
  for (int ct = 0; ct < 8; ++ct) {
    const int col = ct * 16 + l15;
    float bb;
    if constexpr (F32) bb = ((const float*)bw)[col];
    else               bb = tof(((const bf16*)bw)[col]);
#pragma unroll
    for (int r = 0; r < 4; ++r) {
      const float v = acc[ct][r] + bb;
      const float sg = 1.0f / (1.0f + exp2f(-1.44269504f * v));
      const float th = 1.0f - 2.0f / (exp2f(2.88539008f * v) + 1.0f);
      ea_all[(lr0 + quad * 4 + r) * D_ + col] = pk(sg, th);
    }
  }
  float bks[4];
#pragma unroll
  for (int g = 0; g < 4; ++g) bks[g] = bk[g * 16 + l15];
#pragma unroll
  for (int r = 0; r < 4; ++r) {
    float s[4];
    float mx = -1e30f;
#pragma unroll
    for (int g = 0; g < 4; ++g) {
      s[g] = acc[8 + g][r] + bks[g];
      mx = fmaxf(mx, s[g]);
    }
#pragma unroll
    for (int off = 1; off < 16; off <<= 1) mx = fmaxf(mx, __shfl_xor(mx, off, 64));
    float ex[4], sum = 0.f;
#pragma unroll
    for (int g = 0; g < 4; ++g) {
      ex[g] = exp2f(1.44269504f * (s[g] - mx));
      sum += ex[g];
    }
#pragma unroll
    for (int off = 1; off < 16; off <<= 1) sum += __shfl_xor(sum, off, 64);
    const float inv = 1.0f / sum;
    const long lr = lr0 + quad * 4 + r;
#pragma unroll
    for (int g = 0; g < 4; ++g)
      w_all[lr * M_ + g * 16 + l15] = ex[g] * inv;
  }
}

__global__ __launch_bounds__(256, 2) void k1_mfma(const void* x, const void* bw,
                                                  const float* bk, const bf16* WTh,
                                                  const bf16* WTl, uint32* ea_all,
                                                  float* w_all, int chunk, int TL,
                                                  int tshift,
                                                  const int* __restrict__ flag) {
  if (*flag) k1_body<true>(x, bw, bk, WTh, WTl, ea_all, w_all, chunk, TL, tshift);
  else       k1_body<false>(x, bw, bk, WTh, WTl, ea_all, w_all, chunk, TL, tshift);
}

// ---------------- K2: LDS-staged scan, 8m x 1d per thread ---------------------------
// grid = B*4 blocks: b = blk&127, dq = blk>>7 (d range = dq*32..+32).
// Block = 256 thr = 4 waves. lane: mg = lane&7 (m = mg*8..+8), dloc = lane>>3;
// d = dq*32 + wave*8 + dloc. Mv[8] in regs. 16-step tiles double-buffered in
// LDS (ea 2KB + w 4KB per buf) via gl16 by waves 0-2; one barrier per tile.
// Per step: ds_read_b32(ea bcast) + 2x ds_read_b128(w) + 2 unp + 24 fma +
// 3 shfl + 1/8 store.
template <typename T>
__device__ void k2_body(const T* Mv0, const uint32* ea_all, const float* w_all,
                        float* MvS, T* r_out, int chunk, int TL, int TC) {
  const int tid = threadIdx.x;
  const int wave = tid >> 6, lane = tid & 63;
  const int mg = lane & 7, dloc = lane >> 3;
  const int b = blockIdx.x & 127;
  const int dq = blockIdx.x >> 7;          // 0..3
  const int dl = wave * 8 + dloc;          // 0..31 block-local d
  const int d = dq * 32 + dl;
  const int m0 = mg * 8;

  __shared__ uint32 sEA[2][16][32];  // 4 KB
  __shared__ float  sW[2][16][64];   // 8 KB

  float Mv[8];
  if (chunk == 0) {
#pragma unroll
    for (int j = 0; j < 8; ++j)
      Mv[j] = ldf(Mv0, (long)(m0 + j) * D_ + d);
  } else {
#pragma unroll
    for (int j = 0; j < 8; ++j)
      Mv[j] = MvS[((long)b * M_ + m0 + j) * D_ + d];
  }

  const long lrbase = (long)b * TL;                     // chunk-local
  const long arbase = (long)b * S_ + (long)chunk * TL;  // absolute

  // staging: dest = lds base + lane*16 (hardware adds lane offset).
  // ea tile: 16t x 32d u32 (2KB = 2 gl16); w tile: 16t x 64m f32 (4KB = 4 gl16).
  auto stage = [&](int buf, int t0) {
    if (wave == 0) {
#pragma unroll
      for (int c = 0; c < 2; ++c)
        gl16(&ea_all[(lrbase + t0 + c * 8 + (lane >> 3)) * D_ + dq * 32 +
                     (lane & 7) * 4],
             &sEA[buf][c * 8][0]);
    } else if (wave == 1) {
#pragma unroll
      for (int i = 0; i < 2; ++i)
        gl16(&w_all[(lrbase + t0 + i * 4 + (lane >> 4)) * M_ + (lane & 15) * 4],
             &sW[buf][i * 4][0]);
    } else if (wave == 2) {
#pragma unroll
      for (int i = 2; i < 4; ++i)
        gl16(&w_all[(lrbase + t0 + i * 4 + (lane >> 4)) * M_ + (lane & 15) * 4],
             &sW[buf][i * 4][0]);
    }
  };

  stage(0, 0);
  __syncthreads();

  const int NT = TL / 16;
  for (int kk = 0; kk < NT; ++kk) {
    const int cur = kk & 1;
    if (kk + 1 < NT) stage(cur ^ 1, (kk + 1) * 16);
    const long ab = arbase + kk * 16;
#pragma unroll
    for (int t = 0; t < 16; ++t) {
      float e, a;
      unp(sEA[cur][t][dl], e, a);
      const float4 w0 = *(const float4*)&sW[cur][t][m0];
      const float4 w1 = *(const float4*)&sW[cur][t][m0 + 4];
      const float wv[8] = {w0.x, w0.y, w0.z, w0.w, w1.x, w1.y, w1.z, w1.w};
      float r = 0.f;
#pragma unroll
      for (int j = 0; j < 8; ++j) {
        r = fmaf(wv[j], Mv[j], r);
        Mv[j] = fmaf(wv[j], fmaf(-e, Mv[j], a), Mv[j]);
      }
      r += __shfl_xor(r, 1, 64);
      r += __shfl_xor(r, 2, 64);
      r += __shfl_xor(r, 4, 64);
      if (mg == 0) stf(r_out, (ab + t) * D_ + d, r);
    }
    __syncthreads();
  }

  if (chunk < TC - 1) {
#pragma unroll
    for (int j = 0; j < 8; ++j)
      MvS[((long)b * M_ + m0 + j) * D_ + d] = Mv[j];
  }
}

__global__ __launch_bounds__(256) void k2_scan(const void* Mv0, const uint32* ea_all,
                                               const float* w_all, float* MvS,
                                               void* r_out, int chunk, int TL,
                                               int TC, const int* flag) {
  if (*flag) k2_body<float>((const float*)Mv0, ea_all, w_all, MvS,
                            (float*)r_out, chunk, TL, TC);
  else       k2_body<bf16>((const bf16*)Mv0, ea_all, w_all, MvS,
                           (bf16*)r_out, chunk, TL, TC);
}

// ---------------- K3 (MFMA): y = sigmoid(r @ Wp + bp), in place ----------------------
// F32: r fp32 in d_out, split to bf16 hi/lo in-register, bf16x3 MFMA, write fp32 y
// in place. Each wave owns a disjoint 16-row tile: all reads land in registers
// before any store, so in-place is race-free. B-frags fragment-linear.
template <bool F32>
__device__ void k3_body(const bf16* __restrict__ WpTh, const bf16* __restrict__ WpTl,
                        const void* bpv, void* iov) {
  const int tid = threadIdx.x;
  const int wave = tid >> 6, lane = tid & 63;
  const int l15 = lane & 15, quad = lane >> 4;
  const long row0 = (long)blockIdx.x * 64 + wave * 16;

  s16x8 afh[4], afl[4];
  if constexpr (F32) {
    const float* rr = (const float*)iov + (row0 + l15) * D_ + quad * 8;
#pragma unroll
    for (int k = 0; k < 4; ++k) {
      const float4 u0 = *(const float4*)(rr + k * 32);
      const float4 u1 = *(const float4*)(rr + k * 32 + 4);
      union { s16x8 v; uint32 u[4]; } H, L;
      split2(u0.x, u0.y, H.u[0], L.u[0]);
      split2(u0.z, u0.w, H.u[1], L.u[1]);
      split2(u1.x, u1.y, H.u[2], L.u[2]);
      split2(u1.z, u1.w, H.u[3], L.u[3]);
      afh[k] = H.v;
      afl[k] = L.v;
    }
  } else {
    const bf16* rr = (const bf16*)iov + (row0 + l15) * D_ + quad * 8;
#pragma unroll
    for (int k = 0; k < 4; ++k) afh[k] = *(const s16x8*)(rr + k * 32);
  }

  f32x4 acc[8];
#pragma unroll
  for (int ct = 0; ct < 8; ++ct) acc[ct] = (f32x4){0.f, 0.f, 0.f, 0.f};
  const bf16* fbh = WpTh + lane * 8;
  const bf16* fbl = WpTl + lane * 8;
#pragma unroll
  for (int ct = 0; ct < 8; ++ct) {
#pragma unroll
    for (int k = 0; k < 4; ++k) {
      const s16x8 bh = *(const s16x8*)(fbh + (ct * 4 + k) * 512);
      acc[ct] = __builtin_amdgcn_mfma_f32_16x16x32_bf16(afh[k], bh, acc[ct], 0, 0, 0);
      if constexpr (F32) {
        const s16x8 bl = *(const s16x8*)(fbl + (ct * 4 + k) * 512);
        acc[ct] = __builtin_amdgcn_mfma_f32_16x16x32_bf16(afl[k], bh, acc[ct], 0, 0, 0);
        acc[ct] = __builtin_amdgcn_mfma_f32_16x16x32_bf16(afh[k], bl, acc[ct], 0, 0, 0);
      }
    }
  }
#pragma unroll
  for (int ct = 0; ct < 8; ++ct) {
    const int col = ct * 16 + l15;
    float bb;
    if constexpr (F32) bb = ((const float*)bpv)[col];
    else               bb = tof(((const bf16*)bpv)[col]);
#pragma unroll
    for (int r = 0; r < 4; ++r) {
      const float y = 1.0f / (1.0f + exp2f(-1.44269504f * (acc[ct][r] + bb)));
      if constexpr (F32)
        ((float*)iov)[(row0 + quad * 4 + r) * OUT_ + col] = y;
      else
        ((bf16*)iov)[(row0 + quad * 4 + r) * OUT_ + col] = tob(y);
    }
  }
}

__global__ __launch_bounds__(256, 2) void k3_mfma(const bf16* __restrict__ WpTh,
                                                  const bf16* __restrict__ WpTl,
                                                  const void* bpv, void* iov,
                                                  const int* __restrict__ flag) {
  if (*flag) k3_body<true>(WpTh, WpTl, bpv, iov);
  else       k3_body<false>(WpTh, WpTl, bpv, iov);
}

extern "C" void kernel_launch(void* const* d_in, const int* in_sizes, int n_in,
                              void* d_out, int out_size, void* d_ws, size_t ws_size,
                              hipStream_t stream) {
  const void* x   = d_in[0];
  const void* mk  = d_in[1];
  const void* mv  = d_in[2];
  const void* Wr  = d_in[3];
  const void* br  = d_in[4];
  const void* Ww  = d_in[5];
  const void* bwv = d_in[6];
  const void* Wp  = d_in[7];
  const void* bp  = d_in[8];

  // Fixed-region layout: flag | Wk fp32 | bk fp32 | WTh/WTl | WpTh/WpTl
  char* ws = (char*)d_ws;
  int*    flag = (int*)ws;
  float*  Wk   = (float*)(ws + 16);
  float*  bk   = (float*)(ws + 16 + 65536);
  bf16*   WTh  = (bf16*)(ws + 65808);
  bf16*   WTl  = WTh + 192 * 256;
  bf16*   WpTh = WTl + 192 * 256;
  bf16*   WpTl = WpTh + 128 * 128;
  char*   dyn  = (char*)(WpTl + 128 * 128);  // ws + 327,952
  const size_t fixed = (size_t)(dyn - ws);

  // Pick TC = smallest chunk count whose buffers fit ws_size.
  // Per chunk-row: ea u32 (D*4 B) + w fp32 (M*4 B).
  int TC = 16;
  for (int c = 1; c <= 16; c <<= 1) {
    const size_t rc = (size_t)NROWS_ / c;
    const size_t need = fixed + rc * (D_ * 4 + M_ * 4) +
                        (c > 1 ? (size_t)B_ * M_ * D_ * 4 : 0) + 1024;
    if (need <= ws_size) { TC = c; break; }
  }
  const int TL = S_ / TC;
  const int tshift = __builtin_ctz(TL / 64);
  const size_t RC = (size_t)NROWS_ / TC;

  uint32* ea_all = (uint32*)dyn;
  float*  w_all  = (float*)(ea_all + RC * D_);
  float*  MvS    = (float*)(w_all + RC * M_);

  k_probe<<<1, 256, 0, stream>>>((const uint32*)x, flag);
  k0_fold<<<(IN_ * M_ + M_ + 255) / 256, 256, 0, stream>>>(Wr, br, mk, Wk, bk, flag);
  k0b_pack<<<256, 256, 0, stream>>>(Ww, Wp, Wk, WTh, WTl, WpTh, WpTl, flag);
  for (int c = 0; c < TC; ++c) {
    k1_mfma<<<(int)(RC / 64), 256, 0, stream>>>(x, bwv, bk, WTh, WTl, ea_all, w_all,
                                                c, TL, tshift, flag);
    k2_scan<<<B_ * 4, 256, 0, stream>>>(mv, ea_all, w_all, MvS, d_out, c, TL, TC,
                                        flag);
  }
  k3_mfma<<<NROWS_ / 64, 256, 0, stream>>>(WpTh, WpTl, bp, d_out, flag);
}